// Round 4
// baseline (761.343 us; speedup 1.0000x reference)
//
#include <hip/hip_runtime.h>
#include <cstdint>
#include <cstddef>

// ---------- types ----------
typedef __bf16 bf16x8 __attribute__((ext_vector_type(8)));
typedef float  f32x4  __attribute__((ext_vector_type(4)));
typedef int    i32x4  __attribute__((ext_vector_type(4)));
typedef unsigned short u16x4 __attribute__((ext_vector_type(4)));

#define DEV __device__ __forceinline__
#define NEGINF (-__builtin_inff())

DEV uint16_t f2bf(float f) {
  union { float f; uint32_t u; } v; v.f = f;
  uint32_t u = v.u;
  u += 0x7FFFu + ((u >> 16) & 1u);   // RNE
  return (uint16_t)(u >> 16);
}
DEV float bf2f(uint16_t h) {
  union { uint32_t u; float f; } v; v.u = ((uint32_t)h) << 16;
  return v.f;
}

// async global->LDS, 16B per lane. LDS dest must be wave-uniform base (+lane*16).
DEV void gload_lds16(const void* g, void* l) {
  __builtin_amdgcn_global_load_lds(
      (const __attribute__((address_space(1))) void*)g,
      (__attribute__((address_space(3))) void*)l, 16, 0, 0);
}

// ---------- constants ----------
// B=2 S=2048 HID=2560 NH=20 NKV=5 HD=128 GROUPS=4

// ---------- prep kernels ----------
__global__ void k_f32_to_bf16(const float* __restrict__ in, uint16_t* __restrict__ out, int n4) {
  int i = blockIdx.x * blockDim.x + threadIdx.x;
  if (i >= n4) return;
  f32x4 v = *(const f32x4*)(in + (size_t)i * 4);
  u16x4 o;
  o[0] = f2bf(v[0]); o[1] = f2bf(v[1]); o[2] = f2bf(v[2]); o[3] = f2bf(v[3]);
  *(u16x4*)(out + (size_t)i * 4) = o;
}

// packed (M, K/4) stored as int32 per byte-value (harness promotes integers to int32).
__global__ void k_unpack(const uint32_t* __restrict__ p, uint16_t* __restrict__ w, int total, int Kq) {
  int idx = blockIdx.x * blockDim.x + threadIdx.x;
  if (idx >= total) return;
  int row = idx / Kq, pc = idx - row * Kq;
  int blk = pc >> 5, j = pc & 31;
  uint32_t b = p[idx] & 0xFFu;
  size_t base = (size_t)row * (size_t)(Kq * 4) + (size_t)blk * 128 + j;
  w[base]      = f2bf((float)((b >> 6) & 3u) - 1.0f);
  w[base + 32] = f2bf((float)((b >> 4) & 3u) - 1.0f);
  w[base + 64] = f2bf((float)((b >> 2) & 3u) - 1.0f);
  w[base + 96] = f2bf((float)(b & 3u) - 1.0f);
}

__global__ void k_rope_table(float* __restrict__ cosT, float* __restrict__ sinT) {
  int idx = blockIdx.x * blockDim.x + threadIdx.x;  // 2048*64
  int s = idx >> 6, i = idx & 63;
  float inv = expf((float)i * (-13.122363377404328f / 64.0f));
  float fr = (float)s * inv;
  cosT[idx] = cosf(fr);
  sinT[idx] = sinf(fr);
}

// in-place RoPE on (rows=4096, H heads, 128) bf16; pair (d, d+64)
__global__ void k_rope(uint16_t* __restrict__ buf, const float* __restrict__ cosT,
                       const float* __restrict__ sinT, int H, int total) {
  int idx = blockIdx.x * blockDim.x + threadIdx.x;
  if (idx >= total) return;
  int d = idx & 63;
  int t = idx >> 6;
  int h = t % H;
  int row = t / H;          // 0..4095
  int s = row & 2047;
  size_t base = (size_t)row * (size_t)(H * 128) + (size_t)h * 128 + d;
  float x1 = bf2f(buf[base]), x2 = bf2f(buf[base + 64]);
  float c = cosT[(s << 6) + d], sn = sinT[(s << 6) + d];
  buf[base]      = f2bf(x1 * c - x2 * sn);
  buf[base + 64] = f2bf(x2 * c + x1 * sn);
}

// ---------- GEMM: C[M,N] = A[M,K] * W[N,K]^T ----------
// global_load_lds(16B) staging, linear LDS + XOR-swizzle (row&7)<<4 applied to the
// GLOBAL source address (rule 21) and to the ds_read_b128 fragment reads.
template<int MODE>
__global__ __launch_bounds__(256, 2)
void k_gemm(const uint16_t* __restrict__ A, const uint16_t* __restrict__ W,
            uint16_t* __restrict__ Qo, uint16_t* __restrict__ Ko, uint16_t* __restrict__ Vo,
            float* __restrict__ Fo,
            const float* __restrict__ s0p, const float* __restrict__ s1p, const float* __restrict__ s2p,
            int M, int N, int K)
{
  __shared__ uint16_t As[128 * 64];   // 16 KB, linear [row][64] with col-swizzle
  __shared__ uint16_t Bs[128 * 64];   // 16 KB
  const int tid = threadIdx.x;
  const int n0 = blockIdx.x * 128, m0 = blockIdx.y * 128;
  const int lane = tid & 63, w = tid >> 6;
  const int wm = (w >> 1) * 64, wn = (w & 1) * 64;
  const int lr = lane & 15, lg = lane >> 4, lk = lg * 8;
  const size_t K2 = (size_t)K * 2;
  f32x4 acc[4][4] = {};

  // staging source: thread covers linear LDS bytes o = i*4096 + tid*16.
  // row = o>>7 = i*32 + (tid>>3), colb = (tid&7)*16, swizzled src col:
  const int srow = tid >> 3;                       // 0..31 (+i*32)
  const int cprime = ((tid & 7) * 16) ^ ((srow & 7) << 4);
  const uint8_t* Ag = (const uint8_t*)A + (size_t)(m0 + srow) * K2 + cprime;
  const uint8_t* Wg = (const uint8_t*)W + (size_t)(n0 + srow) * K2 + cprime;
  char* Al = (char*)As + w * 1024;                 // wave-uniform dest (+i*4096)
  char* Bl = (char*)Bs + w * 1024;

  for (size_t k0b = 0; k0b < K2; k0b += 128) {
    #pragma unroll
    for (int i = 0; i < 4; ++i)
      gload_lds16(Ag + (size_t)(i * 32) * K2 + k0b, Al + i * 4096);
    #pragma unroll
    for (int i = 0; i < 4; ++i)
      gload_lds16(Wg + (size_t)(i * 32) * K2 + k0b, Bl + i * 4096);
    __syncthreads();
    #pragma unroll
    for (int kc = 0; kc < 64; kc += 32) {
      bf16x8 a[4], b[4];
      #pragma unroll
      for (int i = 0; i < 4; ++i) {
        const int r = wm + i * 16 + lr;
        a[i] = *(const bf16x8*)((const char*)As + r * 128 + (((kc + lk) * 2) ^ ((r & 7) << 4)));
      }
      #pragma unroll
      for (int j = 0; j < 4; ++j) {
        const int r = wn + j * 16 + lr;
        b[j] = *(const bf16x8*)((const char*)Bs + r * 128 + (((kc + lk) * 2) ^ ((r & 7) << 4)));
      }
      #pragma unroll
      for (int i = 0; i < 4; ++i)
        #pragma unroll
        for (int j = 0; j < 4; ++j)
          acc[i][j] = __builtin_amdgcn_mfma_f32_16x16x32_bf16(a[i], b[j], acc[i][j], 0, 0, 0);
    }
    __syncthreads();
  }

  if (MODE == 0) {
    const float qs = *s0p, ks = *s1p, vs = *s2p;
    #pragma unroll
    for (int i = 0; i < 4; ++i) {
      const int rowb = m0 + wm + i * 16 + lg * 4;
      #pragma unroll
      for (int j = 0; j < 4; ++j) {
        const int col = n0 + wn + j * 16 + lr;
        #pragma unroll
        for (int r = 0; r < 4; ++r) {
          const int rr = rowb + r;
          const float v = acc[i][j][r];
          if (col < 2560) {
            Qo[(size_t)rr * 2560 + col] = f2bf(v * qs);
          } else if (col < 3200) {
            Ko[(size_t)rr * 640 + (col - 2560)] = f2bf(v * ks);
          } else {
            const int n2 = col - 3200;
            const int kvh = n2 >> 7, d = n2 & 127;
            const int bb = rr >> 11, ss = rr & 2047;
            Vo[(((size_t)(bb * 5 + kvh) * 128 + d) << 11) + ss] = f2bf(v * vs);
          }
        }
      }
    }
  } else {
    const float os = *s0p;
    #pragma unroll
    for (int i = 0; i < 4; ++i) {
      const int rowb = m0 + wm + i * 16 + lg * 4;
      #pragma unroll
      for (int j = 0; j < 4; ++j) {
        const int col = n0 + wn + j * 16 + lr;
        #pragma unroll
        for (int r = 0; r < 4; ++r)
          Fo[(size_t)(rowb + r) * N + col] = acc[i][j][r] * os;
      }
    }
  }
}

// ---------- flash attention (swapped-operand, 1 strip/wave) ----------
// Q: (b,s,20,128) bf16 rope'd. K: (b,s,5,128) bf16 rope'd. Vt: (b*5,128,2048) bf16.
// Out Ob: (b,s,20,128) bf16. Causal.
// 256-thread blocks = 4 waves; each wave owns ONE 16-row q-strip. 128 strips/bh.
// Strips assigned DESCENDING so the heaviest waves dispatch first.
// QK^T swapped: sa[t] = mfma(K_frag, Q_frag) -> lane owns q = q0 + (lane&15).
// PV swapped: oa[dc] = mfma(V^T_frag, P_frag) -> rescale is lane-local.
__global__ __launch_bounds__(256)
void k_attn(const uint16_t* __restrict__ Q, const uint16_t* __restrict__ Kb,
            const uint16_t* __restrict__ Vt, uint16_t* __restrict__ Ob)
{
  __shared__ uint16_t p_lds[4][16][88];   // per-wave P tile, stride 88 u16
  const int bh = blockIdx.y;
  const int b = bh / 20, h = bh - b * 20, kvh = h >> 2;
  const int tid = threadIdx.x, lane = tid & 63, w = tid >> 6;
  const int lr = lane & 15, lg = lane >> 4, lk = lg * 8;
  uint16_t (*pl)[88] = p_lds[w];
  const int s = 127 - (blockIdx.x * 4 + w);   // strip id, heavy-first
  const int q0 = s * 16;
  const int kend = q0 + 16;

  const uint16_t* Kbase = Kb + (size_t)b * 2048 * 640 + (size_t)kvh * 128;
  const uint16_t* Vbase = Vt + ((size_t)(b * 5 + kvh) * 128) * 2048;
  const float C = 0.127531019577f;        // (1/sqrt(128)) * log2(e)

  bf16x8 qf[4];
  {
    const size_t qbase = ((size_t)(b * 2048 + q0 + lr)) * 2560 + (size_t)h * 128 + lk;
    #pragma unroll
    for (int c = 0; c < 4; ++c) qf[c] = *(const bf16x8*)&Q[qbase + c * 32];
  }

  float m = NEGINF, l = 0.f;
  f32x4 oa[8] = {};

  #pragma unroll 1
  for (int k0 = 0; k0 < kend; k0 += 64) {
    const bool bound = (k0 + 64 >= kend);   // only the final step can cross the diagonal
    f32x4 sa[4] = {};
    #pragma unroll
    for (int t = 0; t < 4; ++t) {
      #pragma unroll
      for (int c = 0; c < 4; ++c) {
        bf16x8 kf = *(const bf16x8*)&Kbase[(size_t)(k0 + t * 16 + lr) * 640 + c * 32 + lk];
        sa[t] = __builtin_amdgcn_mfma_f32_16x16x32_bf16(kf, qf[c], sa[t], 0, 0, 0);
      }
    }
    float u[16];
    if (bound) {
      #pragma unroll
      for (int t = 0; t < 4; ++t)
        #pragma unroll
        for (int r = 0; r < 4; ++r)
          u[t * 4 + r] = (k0 + t * 16 + lg * 4 + r <= q0 + lr) ? sa[t][r] * C : NEGINF;
    } else {
      #pragma unroll
      for (int t = 0; t < 4; ++t)
        #pragma unroll
        for (int r = 0; r < 4; ++r)
          u[t * 4 + r] = sa[t][r] * C;
    }
    // in-lane max tree (15 fmax) + 2 shuffles
    float m01 = fmaxf(u[0], u[1]),   m23 = fmaxf(u[2], u[3]);
    float m45 = fmaxf(u[4], u[5]),   m67 = fmaxf(u[6], u[7]);
    float m89 = fmaxf(u[8], u[9]),   mab = fmaxf(u[10], u[11]);
    float mcd = fmaxf(u[12], u[13]), mef = fmaxf(u[14], u[15]);
    float mx = fmaxf(fmaxf(fmaxf(m01, m23), fmaxf(m45, m67)),
                     fmaxf(fmaxf(m89, mab), fmaxf(mcd, mef)));
    mx = fmaxf(mx, __shfl_xor(mx, 16));
    mx = fmaxf(mx, __shfl_xor(mx, 32));
    const float mn = fmaxf(m, mx);
    const float resc = __builtin_exp2f(m - mn);
    m = mn;
    float p[16];
    #pragma unroll
    for (int i = 0; i < 16; ++i) p[i] = __builtin_exp2f(u[i] - mn);
    float s0 = (p[0] + p[1]) + (p[2] + p[3]);
    float s1 = (p[4] + p[5]) + (p[6] + p[7]);
    float s2 = (p[8] + p[9]) + (p[10] + p[11]);
    float s3 = (p[12] + p[13]) + (p[14] + p[15]);
    l = l * resc + ((s0 + s1) + (s2 + s3));   // lane-partial; combined at end
    // pack P -> LDS: row q=lr, k = 16t + lg*4 + r
    #pragma unroll
    for (int t = 0; t < 4; ++t) {
      union { __bf16 b4[4]; unsigned long long u64; } pk;
      #pragma unroll
      for (int r = 0; r < 4; ++r) pk.b4[r] = (__bf16)p[t * 4 + r];
      *(unsigned long long*)&pl[lr][t * 16 + lg * 4] = pk.u64;
    }
    #pragma unroll
    for (int dc = 0; dc < 8; ++dc) {
      oa[dc][0] *= resc; oa[dc][1] *= resc; oa[dc][2] *= resc; oa[dc][3] *= resc;
    }
    bf16x8 pa0 = *(const bf16x8*)&pl[lr][lk];
    bf16x8 pa1 = *(const bf16x8*)&pl[lr][32 + lk];
    #pragma unroll
    for (int dc = 0; dc < 8; ++dc) {
      bf16x8 vf0 = *(const bf16x8*)&Vbase[(size_t)(dc * 16 + lr) * 2048 + k0 + lk];
      bf16x8 vf1 = *(const bf16x8*)&Vbase[(size_t)(dc * 16 + lr) * 2048 + k0 + 32 + lk];
      oa[dc] = __builtin_amdgcn_mfma_f32_16x16x32_bf16(vf0, pa0, oa[dc], 0, 0, 0);
      oa[dc] = __builtin_amdgcn_mfma_f32_16x16x32_bf16(vf1, pa1, oa[dc], 0, 0, 0);
    }
  }

  float lf = l;
  lf += __shfl_xor(lf, 16);
  lf += __shfl_xor(lf, 32);
  const float inv = 1.0f / lf;
  // oa[dc] rows = d-local (lg*4+r), col = q = q0+lr
  const size_t obase = ((size_t)(b * 2048 + q0 + lr)) * 2560 + (size_t)h * 128;
  #pragma unroll
  for (int dc = 0; dc < 8; ++dc) {
    union { __bf16 b4[4]; unsigned long long u64; } ok;
    #pragma unroll
    for (int r = 0; r < 4; ++r) ok.b4[r] = (__bf16)(oa[dc][r] * inv);
    *(unsigned long long*)&Ob[obase + dc * 16 + lg * 4] = ok.u64;
  }
}

// ---------- RMSNorm over rows of 2560 ----------
__global__ __launch_bounds__(256)
void k_rmsnorm(const uint16_t* __restrict__ X, const float* __restrict__ g, uint16_t* __restrict__ Y)
{
  const int row = blockIdx.x;
  const int tid = threadIdx.x;
  const uint16_t* x = X + (size_t)row * 2560;
  float ss = 0.f;
  #pragma unroll
  for (int it = 0; it < 10; ++it) {
    const int i = tid + it * 256;
    const float v = bf2f(x[i]);
    ss += v * v;
  }
  #pragma unroll
  for (int off = 1; off < 64; off <<= 1) ss += __shfl_xor(ss, off, 64);
  __shared__ float sred[4];
  if ((tid & 63) == 0) sred[tid >> 6] = ss;
  __syncthreads();
  const float tot = sred[0] + sred[1] + sred[2] + sred[3];
  const float rs = rsqrtf(tot * (1.0f / 2560.0f) + 1e-6f);
  uint16_t* y = Y + (size_t)row * 2560;
  #pragma unroll
  for (int it = 0; it < 10; ++it) {
    const int i = tid + it * 256;
    y[i] = f2bf(bf2f(x[i]) * rs * g[i]);
  }
}

// ---------- launch ----------
extern "C" void kernel_launch(void* const* d_in, const int* in_sizes, int n_in,
                              void* d_out, int out_size, void* d_ws, size_t ws_size,
                              hipStream_t stream)
{
  const float*    x     = (const float*)d_in[0];
  // d_in[1] = attention_mask (pure causal -> analytic)
  const uint32_t* qw    = (const uint32_t*)d_in[2];  // harness promotes uint8 -> int32
  const uint32_t* kw    = (const uint32_t*)d_in[3];
  const uint32_t* vw    = (const uint32_t*)d_in[4];
  const uint32_t* ow    = (const uint32_t*)d_in[5];
  const float*    qs    = (const float*)d_in[6];
  const float*    ks    = (const float*)d_in[7];
  const float*    vs    = (const float*)d_in[8];
  const float*    os    = (const float*)d_in[9];
  const float*    gnorm = (const float*)d_in[10];

  char* ws = (char*)d_ws;
  uint16_t* xb   = (uint16_t*)(ws + 0);         // 4096x2560 bf16 (x; reused as attn-out)
  uint16_t* wqkv = (uint16_t*)(ws + 20971520);  // 3840x2560 bf16
  uint16_t* owb  = (uint16_t*)(ws + 40632320);  // 2560x2560 bf16
  float*    cosT = (float*)   (ws + 53739520);  // 2048x64 f32
  float*    sinT = (float*)   (ws + 54263808);  // 2048x64 f32
  uint16_t* Qb   = (uint16_t*)(ws + 54788096);  // 4096x2560 bf16 (reused as normed)
  uint16_t* Kb   = (uint16_t*)(ws + 75759616);  // 4096x640 bf16
  uint16_t* Vt   = (uint16_t*)(ws + 81002496);  // 10x128x2048 bf16

  k_f32_to_bf16<<<10240, 256, 0, stream>>>(x, xb, 2621440);
  k_unpack<<<6400, 256, 0, stream>>>(qw, wqkv, 1638400, 640);
  k_unpack<<<1600, 256, 0, stream>>>(kw, wqkv + (size_t)2560 * 2560, 409600, 640);
  k_unpack<<<1600, 256, 0, stream>>>(vw, wqkv + (size_t)3200 * 2560, 409600, 640);
  k_unpack<<<6400, 256, 0, stream>>>(ow, owb, 1638400, 640);
  k_rope_table<<<512, 256, 0, stream>>>(cosT, sinT);

  k_gemm<0><<<dim3(30, 32), 256, 0, stream>>>(xb, wqkv, Qb, Kb, Vt, nullptr,
                                              qs, ks, vs, 4096, 3840, 2560);
  k_rope<<<20480, 256, 0, stream>>>(Qb, cosT, sinT, 20, 5242880);
  k_rope<<<5120, 256, 0, stream>>>(Kb, cosT, sinT, 5, 1310720);

  k_attn<<<dim3(32, 40), 256, 0, stream>>>(Qb, Kb, Vt, xb);

  k_rmsnorm<<<4096, 256, 0, stream>>>(xb, gnorm, Qb);

  k_gemm<1><<<dim3(20, 32), 256, 0, stream>>>(Qb, owb, nullptr, nullptr, nullptr,
                                              (float*)d_out, os, nullptr, nullptr,
                                              4096, 2560, 2560);
}

// Round 6
// 543.224 us; speedup vs baseline: 1.4015x; 1.4015x over previous
//
#include <hip/hip_runtime.h>
#include <cstdint>
#include <cstddef>

// ---------- types ----------
typedef __bf16 bf16x8 __attribute__((ext_vector_type(8)));
typedef float  f32x4  __attribute__((ext_vector_type(4)));
typedef int    i32x4  __attribute__((ext_vector_type(4)));
typedef unsigned short u16x4 __attribute__((ext_vector_type(4)));

#define DEV __device__ __forceinline__
#define NEGINF (-__builtin_inff())

DEV uint16_t f2bf(float f) {
  union { float f; uint32_t u; } v; v.f = f;
  uint32_t u = v.u;
  u += 0x7FFFu + ((u >> 16) & 1u);   // RNE
  return (uint16_t)(u >> 16);
}
DEV float bf2f(uint16_t h) {
  union { uint32_t u; float f; } v; v.u = ((uint32_t)h) << 16;
  return v.f;
}

// async global->LDS, 16B per lane. LDS dest must be wave-uniform base (+lane*16).
DEV void gload_lds16(const void* g, void* l) {
  __builtin_amdgcn_global_load_lds(
      (const __attribute__((address_space(1))) void*)g,
      (__attribute__((address_space(3))) void*)l, 16, 0, 0);
}

// ---------- constants ----------
// B=2 S=2048 HID=2560 NH=20 NKV=5 HD=128 GROUPS=4

// ---------- prep kernels ----------
__global__ void k_f32_to_bf16(const float* __restrict__ in, uint16_t* __restrict__ out, int n4) {
  int i = blockIdx.x * blockDim.x + threadIdx.x;
  if (i >= n4) return;
  f32x4 v = *(const f32x4*)(in + (size_t)i * 4);
  u16x4 o;
  o[0] = f2bf(v[0]); o[1] = f2bf(v[1]); o[2] = f2bf(v[2]); o[3] = f2bf(v[3]);
  *(u16x4*)(out + (size_t)i * 4) = o;
}

// packed (M, K/4) stored as int32 per byte-value (harness promotes integers to int32).
__global__ void k_unpack(const uint32_t* __restrict__ p, uint16_t* __restrict__ w, int total, int Kq) {
  int idx = blockIdx.x * blockDim.x + threadIdx.x;
  if (idx >= total) return;
  int row = idx / Kq, pc = idx - row * Kq;
  int blk = pc >> 5, j = pc & 31;
  uint32_t b = p[idx] & 0xFFu;
  size_t base = (size_t)row * (size_t)(Kq * 4) + (size_t)blk * 128 + j;
  w[base]      = f2bf((float)((b >> 6) & 3u) - 1.0f);
  w[base + 32] = f2bf((float)((b >> 4) & 3u) - 1.0f);
  w[base + 64] = f2bf((float)((b >> 2) & 3u) - 1.0f);
  w[base + 96] = f2bf((float)(b & 3u) - 1.0f);
}

__global__ void k_rope_table(float* __restrict__ cosT, float* __restrict__ sinT) {
  int idx = blockIdx.x * blockDim.x + threadIdx.x;  // 2048*64
  int s = idx >> 6, i = idx & 63;
  float inv = expf((float)i * (-13.122363377404328f / 64.0f));
  float fr = (float)s * inv;
  cosT[idx] = cosf(fr);
  sinT[idx] = sinf(fr);
}

// in-place RoPE on (rows=4096, H heads, 128) bf16; pair (d, d+64)
__global__ void k_rope(uint16_t* __restrict__ buf, const float* __restrict__ cosT,
                       const float* __restrict__ sinT, int H, int total) {
  int idx = blockIdx.x * blockDim.x + threadIdx.x;
  if (idx >= total) return;
  int d = idx & 63;
  int t = idx >> 6;
  int h = t % H;
  int row = t / H;          // 0..4095
  int s = row & 2047;
  size_t base = (size_t)row * (size_t)(H * 128) + (size_t)h * 128 + d;
  float x1 = bf2f(buf[base]), x2 = bf2f(buf[base + 64]);
  float c = cosT[(s << 6) + d], sn = sinT[(s << 6) + d];
  buf[base]      = f2bf(x1 * c - x2 * sn);
  buf[base + 64] = f2bf(x2 * c + x1 * sn);
}

// ---------- GEMM: C[M,N] = A[M,K] * W[N,K]^T ----------
// global_load_lds(16B) staging, linear LDS + XOR-swizzle (row&7)<<4 applied to the
// GLOBAL source address (rule 21) and to the ds_read_b128 fragment reads.
template<int MODE>
__global__ __launch_bounds__(256, 2)
void k_gemm(const uint16_t* __restrict__ A, const uint16_t* __restrict__ W,
            uint16_t* __restrict__ Qo, uint16_t* __restrict__ Ko, uint16_t* __restrict__ Vo,
            float* __restrict__ Fo,
            const float* __restrict__ s0p, const float* __restrict__ s1p, const float* __restrict__ s2p,
            int M, int N, int K)
{
  __shared__ uint16_t As[128 * 64];   // 16 KB, linear [row][64] with col-swizzle
  __shared__ uint16_t Bs[128 * 64];   // 16 KB
  const int tid = threadIdx.x;
  const int n0 = blockIdx.x * 128, m0 = blockIdx.y * 128;
  const int lane = tid & 63, w = tid >> 6;
  const int wm = (w >> 1) * 64, wn = (w & 1) * 64;
  const int lr = lane & 15, lg = lane >> 4, lk = lg * 8;
  const size_t K2 = (size_t)K * 2;
  f32x4 acc[4][4] = {};

  const int srow = tid >> 3;                       // 0..31 (+i*32)
  const int cprime = ((tid & 7) * 16) ^ ((srow & 7) << 4);
  const uint8_t* Ag = (const uint8_t*)A + (size_t)(m0 + srow) * K2 + cprime;
  const uint8_t* Wg = (const uint8_t*)W + (size_t)(n0 + srow) * K2 + cprime;
  char* Al = (char*)As + w * 1024;                 // wave-uniform dest (+i*4096)
  char* Bl = (char*)Bs + w * 1024;

  for (size_t k0b = 0; k0b < K2; k0b += 128) {
    #pragma unroll
    for (int i = 0; i < 4; ++i)
      gload_lds16(Ag + (size_t)(i * 32) * K2 + k0b, Al + i * 4096);
    #pragma unroll
    for (int i = 0; i < 4; ++i)
      gload_lds16(Wg + (size_t)(i * 32) * K2 + k0b, Bl + i * 4096);
    __syncthreads();
    #pragma unroll
    for (int kc = 0; kc < 64; kc += 32) {
      bf16x8 a[4], b[4];
      #pragma unroll
      for (int i = 0; i < 4; ++i) {
        const int r = wm + i * 16 + lr;
        a[i] = *(const bf16x8*)((const char*)As + r * 128 + (((kc + lk) * 2) ^ ((r & 7) << 4)));
      }
      #pragma unroll
      for (int j = 0; j < 4; ++j) {
        const int r = wn + j * 16 + lr;
        b[j] = *(const bf16x8*)((const char*)Bs + r * 128 + (((kc + lk) * 2) ^ ((r & 7) << 4)));
      }
      #pragma unroll
      for (int i = 0; i < 4; ++i)
        #pragma unroll
        for (int j = 0; j < 4; ++j)
          acc[i][j] = __builtin_amdgcn_mfma_f32_16x16x32_bf16(a[i], b[j], acc[i][j], 0, 0, 0);
    }
    __syncthreads();
  }

  if (MODE == 0) {
    const float qs = *s0p, ks = *s1p, vs = *s2p;
    #pragma unroll
    for (int i = 0; i < 4; ++i) {
      const int rowb = m0 + wm + i * 16 + lg * 4;
      #pragma unroll
      for (int j = 0; j < 4; ++j) {
        const int col = n0 + wn + j * 16 + lr;
        #pragma unroll
        for (int r = 0; r < 4; ++r) {
          const int rr = rowb + r;
          const float v = acc[i][j][r];
          if (col < 2560) {
            Qo[(size_t)rr * 2560 + col] = f2bf(v * qs);
          } else if (col < 3200) {
            Ko[(size_t)rr * 640 + (col - 2560)] = f2bf(v * ks);
          } else {
            const int n2 = col - 3200;
            const int kvh = n2 >> 7, d = n2 & 127;
            const int bb = rr >> 11, ss = rr & 2047;
            Vo[(((size_t)(bb * 5 + kvh) * 128 + d) << 11) + ss] = f2bf(v * vs);
          }
        }
      }
    }
  } else {
    const float os = *s0p;
    #pragma unroll
    for (int i = 0; i < 4; ++i) {
      const int rowb = m0 + wm + i * 16 + lg * 4;
      #pragma unroll
      for (int j = 0; j < 4; ++j) {
        const int col = n0 + wn + j * 16 + lr;
        #pragma unroll
        for (int r = 0; r < 4; ++r)
          Fo[(size_t)(rowb + r) * N + col] = acc[i][j][r] * os;
      }
    }
  }
}

// ---------- flash attention (swapped-operand, paired strips + split-K) ----------
// Q: (b,s,20,128) bf16 rope'd. K: (b,s,5,128) bf16 rope'd. Vt: (b*5,128,2048) bf16.
// Out Ob: (b,s,20,128) bf16. Causal.
// Wave task = (pair p, k-half hf). Wave processes strips {p, 127-p}, only its
// k-half of each -> every wave ~16.5 equal k-steps (uniform), 5120 waves total.
// Waves 2j (hf=0) and 2j+1 (hf=1) of a block merge partials via LDS.
// QK^T swapped: lane owns q = q0+(lane&15); scores k = k0+16t+(lane>>4)*4+r.
// PV swapped: O^T layout -> m/l/rescale all lane-local, so split-K merge is
// a pure per-lane elementwise combine.
__global__ __launch_bounds__(256)
void k_attn(const uint16_t* __restrict__ Q, const uint16_t* __restrict__ Kb,
            const uint16_t* __restrict__ Vt, uint16_t* __restrict__ Ob)
{
  __shared__ uint16_t p_lds[4][16][88];   // per-wave P tile
  __shared__ float mbuf[2][64][36];       // per-pair merge buffer (oa[32], m, l)
  const int bh = blockIdx.y;
  const int b = bh / 20, h = bh - b * 20, kvh = h >> 2;
  const int tid = threadIdx.x, lane = tid & 63, w = tid >> 6;
  const int lr = lane & 15, lg = lane >> 4, lk = lg * 8;
  uint16_t (*pl)[88] = p_lds[w];
  const int wg = blockIdx.x * 4 + w;      // 0..127
  const int p = wg >> 1;                  // pair id 0..63
  const int hf = wg & 1;                  // k-half
  const int pslot = w >> 1;               // pair slot within block (0,1)

  const uint16_t* Kbase = Kb + (size_t)b * 2048 * 640 + (size_t)kvh * 128;
  const uint16_t* Vbase = Vt + ((size_t)(b * 5 + kvh) * 128) * 2048;
  const float C = 0.127531019577f;        // (1/sqrt(128)) * log2(e)

  #pragma unroll 1
  for (int sel = 0; sel < 2; ++sel) {
    const int st = sel ? (127 - p) : p;
    const int q0 = st * 16;
    const int kend = q0 + 16;
    const int ns = (q0 + 79) >> 6;        // total 64-wide k-steps for this strip
    const int nh0 = ns >> 1;
    const int stp_begin = hf ? nh0 : 0;
    const int stp_end   = hf ? ns  : nh0;

    bf16x8 qf[4];
    {
      const size_t qbase = ((size_t)(b * 2048 + q0 + lr)) * 2560 + (size_t)h * 128 + lk;
      #pragma unroll
      for (int c = 0; c < 4; ++c) qf[c] = *(const bf16x8*)&Q[qbase + c * 32];
    }

    float m = NEGINF, l = 0.f;
    f32x4 oa[8] = {};

    #pragma unroll 1
    for (int stp = stp_begin; stp < stp_end; ++stp) {
      const int k0 = stp * 64;
      const bool bound = (k0 + 64 >= kend);   // only the final step crosses the diagonal
      f32x4 sa[4] = {};
      #pragma unroll
      for (int t = 0; t < 4; ++t) {
        #pragma unroll
        for (int c = 0; c < 4; ++c) {
          bf16x8 kf = *(const bf16x8*)&Kbase[(size_t)(k0 + t * 16 + lr) * 640 + c * 32 + lk];
          sa[t] = __builtin_amdgcn_mfma_f32_16x16x32_bf16(kf, qf[c], sa[t], 0, 0, 0);
        }
      }
      float u[16];
      if (bound) {
        #pragma unroll
        for (int t = 0; t < 4; ++t)
          #pragma unroll
          for (int r = 0; r < 4; ++r)
            u[t * 4 + r] = (k0 + t * 16 + lg * 4 + r <= q0 + lr) ? sa[t][r] * C : NEGINF;
      } else {
        #pragma unroll
        for (int t = 0; t < 4; ++t)
          #pragma unroll
          for (int r = 0; r < 4; ++r)
            u[t * 4 + r] = sa[t][r] * C;
      }
      // in-lane max tree (15 fmax) + 2 shuffles (reduce across lg groups)
      float m01 = fmaxf(u[0], u[1]),   m23 = fmaxf(u[2], u[3]);
      float m45 = fmaxf(u[4], u[5]),   m67 = fmaxf(u[6], u[7]);
      float m89 = fmaxf(u[8], u[9]),   mab = fmaxf(u[10], u[11]);
      float mcd = fmaxf(u[12], u[13]), mef = fmaxf(u[14], u[15]);
      float mx = fmaxf(fmaxf(fmaxf(m01, m23), fmaxf(m45, m67)),
                       fmaxf(fmaxf(m89, mab), fmaxf(mcd, mef)));
      mx = fmaxf(mx, __shfl_xor(mx, 16));
      mx = fmaxf(mx, __shfl_xor(mx, 32));
      const float mn = fmaxf(m, mx);
      const float resc = __builtin_exp2f(m - mn);
      m = mn;
      float pv[16];
      #pragma unroll
      for (int i = 0; i < 16; ++i) pv[i] = __builtin_exp2f(u[i] - mn);
      float s0 = (pv[0] + pv[1]) + (pv[2] + pv[3]);
      float s1 = (pv[4] + pv[5]) + (pv[6] + pv[7]);
      float s2 = (pv[8] + pv[9]) + (pv[10] + pv[11]);
      float s3 = (pv[12] + pv[13]) + (pv[14] + pv[15]);
      l = l * resc + ((s0 + s1) + (s2 + s3));   // lane-partial; combined after merge
      // pack P -> LDS: row q=lr, k = 16t + lg*4 + r
      #pragma unroll
      for (int t = 0; t < 4; ++t) {
        union { __bf16 b4[4]; unsigned long long u64; } pk;
        #pragma unroll
        for (int r = 0; r < 4; ++r) pk.b4[r] = (__bf16)pv[t * 4 + r];
        *(unsigned long long*)&pl[lr][t * 16 + lg * 4] = pk.u64;
      }
      #pragma unroll
      for (int dc = 0; dc < 8; ++dc) {
        oa[dc][0] *= resc; oa[dc][1] *= resc; oa[dc][2] *= resc; oa[dc][3] *= resc;
      }
      bf16x8 pa0 = *(const bf16x8*)&pl[lr][lk];
      bf16x8 pa1 = *(const bf16x8*)&pl[lr][32 + lk];
      #pragma unroll
      for (int dc = 0; dc < 8; ++dc) {
        bf16x8 vf0 = *(const bf16x8*)&Vbase[(size_t)(dc * 16 + lr) * 2048 + k0 + lk];
        bf16x8 vf1 = *(const bf16x8*)&Vbase[(size_t)(dc * 16 + lr) * 2048 + k0 + 32 + lk];
        oa[dc] = __builtin_amdgcn_mfma_f32_16x16x32_bf16(vf0, pa0, oa[dc], 0, 0, 0);
        oa[dc] = __builtin_amdgcn_mfma_f32_16x16x32_bf16(vf1, pa1, oa[dc], 0, 0, 0);
      }
    }

    // ---- split-K merge: hf=1 publishes, hf=0 merges + stores ----
    if (hf) {
      float* dst = &mbuf[pslot][lane][0];
      #pragma unroll
      for (int dc = 0; dc < 8; ++dc) *(f32x4*)(dst + dc * 4) = oa[dc];
      dst[32] = m; dst[33] = l;
    }
    __syncthreads();
    if (!hf) {
      const float* src = &mbuf[pslot][lane][0];
      const float m1 = src[32], l1 = src[33];
      const float mn = fmaxf(m, m1);
      const float a0 = __builtin_exp2f(m - mn);    // m=-inf only when other finite
      const float a1 = __builtin_exp2f(m1 - mn);
      float lm = l * a0 + l1 * a1;
      lm += __shfl_xor(lm, 16);
      lm += __shfl_xor(lm, 32);
      const float inv = 1.0f / lm;
      const size_t obase = ((size_t)(b * 2048 + q0 + lr)) * 2560 + (size_t)h * 128;
      #pragma unroll
      for (int dc = 0; dc < 8; ++dc) {
        f32x4 o1 = *(const f32x4*)(src + dc * 4);
        union { __bf16 b4[4]; unsigned long long u64; } ok;
        #pragma unroll
        for (int r = 0; r < 4; ++r)
          ok.b4[r] = (__bf16)((oa[dc][r] * a0 + o1[r] * a1) * inv);
        *(unsigned long long*)&Ob[obase + dc * 16 + lg * 4] = ok.u64;
      }
    }
    __syncthreads();
  }
}

// ---------- RMSNorm over rows of 2560 ----------
__global__ __launch_bounds__(256)
void k_rmsnorm(const uint16_t* __restrict__ X, const float* __restrict__ g, uint16_t* __restrict__ Y)
{
  const int row = blockIdx.x;
  const int tid = threadIdx.x;
  const uint16_t* x = X + (size_t)row * 2560;
  float ss = 0.f;
  #pragma unroll
  for (int it = 0; it < 10; ++it) {
    const int i = tid + it * 256;
    const float v = bf2f(x[i]);
    ss += v * v;
  }
  #pragma unroll
  for (int off = 1; off < 64; off <<= 1) ss += __shfl_xor(ss, off, 64);
  __shared__ float sred[4];
  if ((tid & 63) == 0) sred[tid >> 6] = ss;
  __syncthreads();
  const float tot = sred[0] + sred[1] + sred[2] + sred[3];
  const float rs = rsqrtf(tot * (1.0f / 2560.0f) + 1e-6f);
  uint16_t* y = Y + (size_t)row * 2560;
  #pragma unroll
  for (int it = 0; it < 10; ++it) {
    const int i = tid + it * 256;
    y[i] = f2bf(bf2f(x[i]) * rs * g[i]);
  }
}

// ---------- launch ----------
extern "C" void kernel_launch(void* const* d_in, const int* in_sizes, int n_in,
                              void* d_out, int out_size, void* d_ws, size_t ws_size,
                              hipStream_t stream)
{
  const float*    x     = (const float*)d_in[0];
  // d_in[1] = attention_mask (pure causal -> analytic)
  const uint32_t* qw    = (const uint32_t*)d_in[2];  // harness promotes uint8 -> int32
  const uint32_t* kw    = (const uint32_t*)d_in[3];
  const uint32_t* vw    = (const uint32_t*)d_in[4];
  const uint32_t* ow    = (const uint32_t*)d_in[5];
  const float*    qs    = (const float*)d_in[6];
  const float*    ks    = (const float*)d_in[7];
  const float*    vs    = (const float*)d_in[8];
  const float*    os    = (const float*)d_in[9];
  const float*    gnorm = (const float*)d_in[10];

  char* ws = (char*)d_ws;
  uint16_t* xb   = (uint16_t*)(ws + 0);         // 4096x2560 bf16 (x; reused as attn-out)
  uint16_t* wqkv = (uint16_t*)(ws + 20971520);  // 3840x2560 bf16
  uint16_t* owb  = (uint16_t*)(ws + 40632320);  // 2560x2560 bf16
  float*    cosT = (float*)   (ws + 53739520);  // 2048x64 f32
  float*    sinT = (float*)   (ws + 54263808);  // 2048x64 f32
  uint16_t* Qb   = (uint16_t*)(ws + 54788096);  // 4096x2560 bf16 (reused as normed)
  uint16_t* Kb   = (uint16_t*)(ws + 75759616);  // 4096x640 bf16
  uint16_t* Vt   = (uint16_t*)(ws + 81002496);  // 10x128x2048 bf16

  k_f32_to_bf16<<<10240, 256, 0, stream>>>(x, xb, 2621440);
  k_unpack<<<6400, 256, 0, stream>>>(qw, wqkv, 1638400, 640);
  k_unpack<<<1600, 256, 0, stream>>>(kw, wqkv + (size_t)2560 * 2560, 409600, 640);
  k_unpack<<<1600, 256, 0, stream>>>(vw, wqkv + (size_t)3200 * 2560, 409600, 640);
  k_unpack<<<6400, 256, 0, stream>>>(ow, owb, 1638400, 640);
  k_rope_table<<<512, 256, 0, stream>>>(cosT, sinT);

  k_gemm<0><<<dim3(30, 32), 256, 0, stream>>>(xb, wqkv, Qb, Kb, Vt, nullptr,
                                              qs, ks, vs, 4096, 3840, 2560);
  k_rope<<<20480, 256, 0, stream>>>(Qb, cosT, sinT, 20, 5242880);
  k_rope<<<5120, 256, 0, stream>>>(Kb, cosT, sinT, 5, 1310720);

  k_attn<<<dim3(32, 40), 256, 0, stream>>>(Qb, Kb, Vt, xb);

  k_rmsnorm<<<4096, 256, 0, stream>>>(xb, gnorm, Qb);

  k_gemm<1><<<dim3(20, 32), 256, 0, stream>>>(Qb, owb, nullptr, nullptr, nullptr,
                                              (float*)d_out, os, nullptr, nullptr,
                                              4096, 2560, 2560);
}

// Round 7
// 335.295 us; speedup vs baseline: 2.2707x; 1.6201x over previous
//
#include <hip/hip_runtime.h>
#include <cstdint>
#include <cstddef>

// ---------- types ----------
typedef __bf16 bf16x8 __attribute__((ext_vector_type(8)));
typedef float  f32x4  __attribute__((ext_vector_type(4)));
typedef int    i32x4  __attribute__((ext_vector_type(4)));
typedef unsigned short u16x4 __attribute__((ext_vector_type(4)));

#define DEV __device__ __forceinline__
#define NEGINF (-__builtin_inff())

DEV uint16_t f2bf(float f) {
  union { float f; uint32_t u; } v; v.f = f;
  uint32_t u = v.u;
  u += 0x7FFFu + ((u >> 16) & 1u);   // RNE
  return (uint16_t)(u >> 16);
}
DEV float bf2f(uint16_t h) {
  union { uint32_t u; float f; } v; v.u = ((uint32_t)h) << 16;
  return v.f;
}

// async global->LDS, 16B per lane. LDS dest must be wave-uniform base (+lane*16).
DEV void gload_lds16(const void* g, void* l) {
  __builtin_amdgcn_global_load_lds(
      (const __attribute__((address_space(1))) void*)g,
      (__attribute__((address_space(3))) void*)l, 16, 0, 0);
}

// ---------- constants ----------
// B=2 S=2048 HID=2560 NH=20 NKV=5 HD=128 GROUPS=4

// ---------- prep kernels ----------
__global__ void k_f32_to_bf16(const float* __restrict__ in, uint16_t* __restrict__ out, int n4) {
  int i = blockIdx.x * blockDim.x + threadIdx.x;
  if (i >= n4) return;
  f32x4 v = *(const f32x4*)(in + (size_t)i * 4);
  u16x4 o;
  o[0] = f2bf(v[0]); o[1] = f2bf(v[1]); o[2] = f2bf(v[2]); o[3] = f2bf(v[3]);
  *(u16x4*)(out + (size_t)i * 4) = o;
}

// packed (M, K/4) stored as int32 per byte-value (harness promotes integers to int32).
__global__ void k_unpack(const uint32_t* __restrict__ p, uint16_t* __restrict__ w, int total, int Kq) {
  int idx = blockIdx.x * blockDim.x + threadIdx.x;
  if (idx >= total) return;
  int row = idx / Kq, pc = idx - row * Kq;
  int blk = pc >> 5, j = pc & 31;
  uint32_t b = p[idx] & 0xFFu;
  size_t base = (size_t)row * (size_t)(Kq * 4) + (size_t)blk * 128 + j;
  w[base]      = f2bf((float)((b >> 6) & 3u) - 1.0f);
  w[base + 32] = f2bf((float)((b >> 4) & 3u) - 1.0f);
  w[base + 64] = f2bf((float)((b >> 2) & 3u) - 1.0f);
  w[base + 96] = f2bf((float)(b & 3u) - 1.0f);
}

__global__ void k_rope_table(float* __restrict__ cosT, float* __restrict__ sinT) {
  int idx = blockIdx.x * blockDim.x + threadIdx.x;  // 2048*64
  int s = idx >> 6, i = idx & 63;
  float inv = expf((float)i * (-13.122363377404328f / 64.0f));
  float fr = (float)s * inv;
  cosT[idx] = cosf(fr);
  sinT[idx] = sinf(fr);
}

// in-place RoPE on (rows=4096, H heads, 128) bf16; pair (d, d+64)
__global__ void k_rope(uint16_t* __restrict__ buf, const float* __restrict__ cosT,
                       const float* __restrict__ sinT, int H, int total) {
  int idx = blockIdx.x * blockDim.x + threadIdx.x;
  if (idx >= total) return;
  int d = idx & 63;
  int t = idx >> 6;
  int h = t % H;
  int row = t / H;          // 0..4095
  int s = row & 2047;
  size_t base = (size_t)row * (size_t)(H * 128) + (size_t)h * 128 + d;
  float x1 = bf2f(buf[base]), x2 = bf2f(buf[base + 64]);
  float c = cosT[(s << 6) + d], sn = sinT[(s << 6) + d];
  buf[base]      = f2bf(x1 * c - x2 * sn);
  buf[base + 64] = f2bf(x2 * c + x1 * sn);
}

// ---------- GEMM: C[M,N] = A[M,K] * W[N,K]^T ----------
// global_load_lds(16B) staging, linear LDS + XOR-swizzle (row&7)<<4 applied to the
// GLOBAL source address (rule 21) and to the ds_read_b128 fragment reads.
template<int MODE>
__global__ __launch_bounds__(256, 2)
void k_gemm(const uint16_t* __restrict__ A, const uint16_t* __restrict__ W,
            uint16_t* __restrict__ Qo, uint16_t* __restrict__ Ko, uint16_t* __restrict__ Vo,
            float* __restrict__ Fo,
            const float* __restrict__ s0p, const float* __restrict__ s1p, const float* __restrict__ s2p,
            int M, int N, int K)
{
  __shared__ uint16_t As[128 * 64];   // 16 KB, linear [row][64] with col-swizzle
  __shared__ uint16_t Bs[128 * 64];   // 16 KB
  const int tid = threadIdx.x;
  const int n0 = blockIdx.x * 128, m0 = blockIdx.y * 128;
  const int lane = tid & 63, w = tid >> 6;
  const int wm = (w >> 1) * 64, wn = (w & 1) * 64;
  const int lr = lane & 15, lg = lane >> 4, lk = lg * 8;
  const size_t K2 = (size_t)K * 2;
  f32x4 acc[4][4] = {};

  const int srow = tid >> 3;                       // 0..31 (+i*32)
  const int cprime = ((tid & 7) * 16) ^ ((srow & 7) << 4);
  const uint8_t* Ag = (const uint8_t*)A + (size_t)(m0 + srow) * K2 + cprime;
  const uint8_t* Wg = (const uint8_t*)W + (size_t)(n0 + srow) * K2 + cprime;
  char* Al = (char*)As + w * 1024;                 // wave-uniform dest (+i*4096)
  char* Bl = (char*)Bs + w * 1024;

  for (size_t k0b = 0; k0b < K2; k0b += 128) {
    #pragma unroll
    for (int i = 0; i < 4; ++i)
      gload_lds16(Ag + (size_t)(i * 32) * K2 + k0b, Al + i * 4096);
    #pragma unroll
    for (int i = 0; i < 4; ++i)
      gload_lds16(Wg + (size_t)(i * 32) * K2 + k0b, Bl + i * 4096);
    __syncthreads();
    #pragma unroll
    for (int kc = 0; kc < 64; kc += 32) {
      bf16x8 a[4], b[4];
      #pragma unroll
      for (int i = 0; i < 4; ++i) {
        const int r = wm + i * 16 + lr;
        a[i] = *(const bf16x8*)((const char*)As + r * 128 + (((kc + lk) * 2) ^ ((r & 7) << 4)));
      }
      #pragma unroll
      for (int j = 0; j < 4; ++j) {
        const int r = wn + j * 16 + lr;
        b[j] = *(const bf16x8*)((const char*)Bs + r * 128 + (((kc + lk) * 2) ^ ((r & 7) << 4)));
      }
      #pragma unroll
      for (int i = 0; i < 4; ++i)
        #pragma unroll
        for (int j = 0; j < 4; ++j)
          acc[i][j] = __builtin_amdgcn_mfma_f32_16x16x32_bf16(a[i], b[j], acc[i][j], 0, 0, 0);
    }
    __syncthreads();
  }

  if (MODE == 0) {
    const float qs = *s0p, ks = *s1p, vs = *s2p;
    #pragma unroll
    for (int i = 0; i < 4; ++i) {
      const int rowb = m0 + wm + i * 16 + lg * 4;
      #pragma unroll
      for (int j = 0; j < 4; ++j) {
        const int col = n0 + wn + j * 16 + lr;
        #pragma unroll
        for (int r = 0; r < 4; ++r) {
          const int rr = rowb + r;
          const float v = acc[i][j][r];
          if (col < 2560) {
            Qo[(size_t)rr * 2560 + col] = f2bf(v * qs);
          } else if (col < 3200) {
            Ko[(size_t)rr * 640 + (col - 2560)] = f2bf(v * ks);
          } else {
            const int n2 = col - 3200;
            const int kvh = n2 >> 7, d = n2 & 127;
            const int bb = rr >> 11, ss = rr & 2047;
            Vo[(((size_t)(bb * 5 + kvh) * 128 + d) << 11) + ss] = f2bf(v * vs);
          }
        }
      }
    }
  } else {
    const float os = *s0p;
    #pragma unroll
    for (int i = 0; i < 4; ++i) {
      const int rowb = m0 + wm + i * 16 + lg * 4;
      #pragma unroll
      for (int j = 0; j < 4; ++j) {
        const int col = n0 + wn + j * 16 + lr;
        #pragma unroll
        for (int r = 0; r < 4; ++r)
          Fo[(size_t)(rowb + r) * N + col] = acc[i][j][r] * os;
      }
    }
  }
}

// ---------- flash attention (GQA-shared LDS-staged K/V, double-buffered) ----------
// Q: (b,s,20,128) bf16 rope'd. K: (b,s,5,128) bf16 rope'd. Vt: (b*5,128,2048) bf16.
// Out Ob: (b,s,20,128) bf16. Causal.
// Block = (b, kvh, pair {p,127-p}); 4 waves = the 4 q-heads of the GQA group,
// all sharing K/V tiles staged in LDS. Per 64-wide k-step:
//   stage(next tile via global_load_lds x8) -> s_waitcnt vmcnt(8) -> barrier
//   -> compute (QK^T from K-LDS, softmax, PV from V-LDS) -> barrier.
// XOR-swizzle (row&7)<<4 on staging SOURCE and ds_read addresses (rule 21).
// QK^T swapped: lane owns q = q0+(lane&15). PV swapped: O^T, rescale lane-local.
__global__ __launch_bounds__(256)
void k_attn(const uint16_t* __restrict__ Q, const uint16_t* __restrict__ Kb,
            const uint16_t* __restrict__ Vt, uint16_t* __restrict__ Ob)
{
  __shared__ char Klds[2][16384];         // [64 k][128 d] bf16, swizzled
  __shared__ char Vlds[2][16384];         // [128 d][64 k] bf16, swizzled
  __shared__ uint16_t p_lds[4][16][88];   // per-wave P tile

  // XCD-chunked remap: keep all pairs of one (b,kvh) on one XCD (L2 locality).
  const int lin = blockIdx.x + (blockIdx.y << 6);        // 0..639
  const int gslot = (lin & 7) * 80 + (lin >> 3);
  const int p = gslot & 63;                              // pair id 0..63
  const int bk = gslot >> 6;                             // 0..9
  const int b = bk / 5, kvh = bk - b * 5;

  const int tid = threadIdx.x, lane = tid & 63, w = tid >> 6;
  const int lr = lane & 15, lg = lane >> 4, lk = lg * 8;
  const int h = kvh * 4 + w;                             // this wave's q-head
  uint16_t (*pl)[88] = p_lds[w];
  const int kswz = (lr & 7) << 4;

  const uint8_t* Kg = (const uint8_t*)(Kb + (size_t)b * 2048 * 640 + (size_t)kvh * 128);
  const uint8_t* Vg = (const uint8_t*)(Vt + ((size_t)(b * 5 + kvh) * 128) * 2048);

  // staging coords (256 threads cover each 16KB tile in 4 x 16B rounds)
  const int krow = tid >> 4;                             // K: row 0..15 (+16i)
  const int kcol = ((tid & 15) * 16) ^ ((krow & 7) << 4);
  const int vrow = tid >> 3;                             // V: row 0..31 (+32i)
  const int vcol = ((tid & 7) * 16) ^ ((vrow & 7) << 4);
  const int dst16 = tid * 16;

  const float C = 0.127531019577f;        // (1/sqrt(128)) * log2(e)

  #pragma unroll 1
  for (int sel = 0; sel < 2; ++sel) {
    const int st = sel ? (127 - p) : p;
    const int q0 = st * 16;
    const int ns = (q0 + 79) >> 6;        // 64-wide k-steps for this strip

    bf16x8 qf[4];
    {
      const size_t qbase = ((size_t)(b * 2048 + q0 + lr)) * 2560 + (size_t)h * 128 + lk;
      #pragma unroll
      for (int c = 0; c < 4; ++c) qf[c] = *(const bf16x8*)&Q[qbase + c * 32];
    }
    asm volatile("s_waitcnt vmcnt(0)" ::: "memory");   // drain Q loads (+prior stores)

    // prologue: stage step 0 into buf 0
    {
      const uint8_t* Ks = Kg + (size_t)krow * 1280 + kcol;
      const uint8_t* Vs = Vg + (size_t)vrow * 4096 + vcol;
      char* Kd = Klds[0] + dst16;
      char* Vd = Vlds[0] + dst16;
      #pragma unroll
      for (int i = 0; i < 4; ++i) gload_lds16(Ks + (size_t)i * 16 * 1280, Kd + i * 4096);
      #pragma unroll
      for (int i = 0; i < 4; ++i) gload_lds16(Vs + (size_t)i * 32 * 4096, Vd + i * 4096);
    }

    int cur = 0;
    float m = NEGINF, l = 0.f;
    f32x4 oa[8] = {};

    #pragma unroll 1
    for (int stp = 0; stp < ns; ++stp) {
      const int k0 = stp * 64;
      if (stp + 1 < ns) {
        const int kn = k0 + 64;
        const uint8_t* Ks = Kg + (size_t)(kn + krow) * 1280 + kcol;
        const uint8_t* Vs = Vg + (size_t)vrow * 4096 + (size_t)kn * 2 + vcol;
        char* Kd = Klds[cur ^ 1] + dst16;
        char* Vd = Vlds[cur ^ 1] + dst16;
        #pragma unroll
        for (int i = 0; i < 4; ++i) gload_lds16(Ks + (size_t)i * 16 * 1280, Kd + i * 4096);
        #pragma unroll
        for (int i = 0; i < 4; ++i) gload_lds16(Vs + (size_t)i * 32 * 4096, Vd + i * 4096);
        asm volatile("s_waitcnt vmcnt(8)" ::: "memory");   // cur-buf loads complete
      } else {
        asm volatile("s_waitcnt vmcnt(0)" ::: "memory");
      }
      __syncthreads();

      const char* Kc = Klds[cur];
      const char* Vc = Vlds[cur];
      const bool bound = (k0 + 64 >= q0 + 16);   // final step crosses the diagonal

      f32x4 sa[4] = {};
      #pragma unroll
      for (int t = 0; t < 4; ++t) {
        #pragma unroll
        for (int c = 0; c < 4; ++c) {
          bf16x8 kf = *(const bf16x8*)(Kc + (t * 16 + lr) * 256 + ((c * 64 + lg * 16) ^ kswz));
          sa[t] = __builtin_amdgcn_mfma_f32_16x16x32_bf16(kf, qf[c], sa[t], 0, 0, 0);
        }
      }
      float u[16];
      if (bound) {
        #pragma unroll
        for (int t = 0; t < 4; ++t)
          #pragma unroll
          for (int r = 0; r < 4; ++r)
            u[t * 4 + r] = (k0 + t * 16 + lg * 4 + r <= q0 + lr) ? sa[t][r] * C : NEGINF;
      } else {
        #pragma unroll
        for (int t = 0; t < 4; ++t)
          #pragma unroll
          for (int r = 0; r < 4; ++r)
            u[t * 4 + r] = sa[t][r] * C;
      }
      // in-lane max tree + 2 shuffles
      float m01 = fmaxf(u[0], u[1]),   m23 = fmaxf(u[2], u[3]);
      float m45 = fmaxf(u[4], u[5]),   m67 = fmaxf(u[6], u[7]);
      float m89 = fmaxf(u[8], u[9]),   mab = fmaxf(u[10], u[11]);
      float mcd = fmaxf(u[12], u[13]), mef = fmaxf(u[14], u[15]);
      float mx = fmaxf(fmaxf(fmaxf(m01, m23), fmaxf(m45, m67)),
                       fmaxf(fmaxf(m89, mab), fmaxf(mcd, mef)));
      mx = fmaxf(mx, __shfl_xor(mx, 16));
      mx = fmaxf(mx, __shfl_xor(mx, 32));
      const float mn = fmaxf(m, mx);
      const float resc = __builtin_exp2f(m - mn);
      m = mn;
      float pv[16];
      #pragma unroll
      for (int i = 0; i < 16; ++i) pv[i] = __builtin_exp2f(u[i] - mn);
      float s0 = (pv[0] + pv[1]) + (pv[2] + pv[3]);
      float s1 = (pv[4] + pv[5]) + (pv[6] + pv[7]);
      float s2 = (pv[8] + pv[9]) + (pv[10] + pv[11]);
      float s3 = (pv[12] + pv[13]) + (pv[14] + pv[15]);
      l = l * resc + ((s0 + s1) + (s2 + s3));
      // pack P -> per-wave LDS: row q=lr, k = 16t + lg*4 + r
      #pragma unroll
      for (int t = 0; t < 4; ++t) {
        union { __bf16 b4[4]; unsigned long long u64; } pk;
        #pragma unroll
        for (int r = 0; r < 4; ++r) pk.b4[r] = (__bf16)pv[t * 4 + r];
        *(unsigned long long*)&pl[lr][t * 16 + lg * 4] = pk.u64;
      }
      #pragma unroll
      for (int dc = 0; dc < 8; ++dc) {
        oa[dc][0] *= resc; oa[dc][1] *= resc; oa[dc][2] *= resc; oa[dc][3] *= resc;
      }
      bf16x8 pa0 = *(const bf16x8*)&pl[lr][lk];
      bf16x8 pa1 = *(const bf16x8*)&pl[lr][32 + lk];
      #pragma unroll
      for (int dc = 0; dc < 8; ++dc) {
        bf16x8 vf0 = *(const bf16x8*)(Vc + (dc * 16 + lr) * 128 + ((lg * 16) ^ kswz));
        bf16x8 vf1 = *(const bf16x8*)(Vc + (dc * 16 + lr) * 128 + ((64 + lg * 16) ^ kswz));
        oa[dc] = __builtin_amdgcn_mfma_f32_16x16x32_bf16(vf0, pa0, oa[dc], 0, 0, 0);
        oa[dc] = __builtin_amdgcn_mfma_f32_16x16x32_bf16(vf1, pa1, oa[dc], 0, 0, 0);
      }
      __syncthreads();   // all waves done reading buf[cur] before it is re-staged
      cur ^= 1;
    }

    float lf = l;
    lf += __shfl_xor(lf, 16);
    lf += __shfl_xor(lf, 32);
    const float inv = 1.0f / lf;
    // oa[dc] rows = d-local (lg*4+r), col = q = q0+lr
    const size_t obase = ((size_t)(b * 2048 + q0 + lr)) * 2560 + (size_t)h * 128;
    #pragma unroll
    for (int dc = 0; dc < 8; ++dc) {
      union { __bf16 b4[4]; unsigned long long u64; } ok;
      #pragma unroll
      for (int r = 0; r < 4; ++r) ok.b4[r] = (__bf16)(oa[dc][r] * inv);
      *(unsigned long long*)&Ob[obase + dc * 16 + lg * 4] = ok.u64;
    }
  }
}

// ---------- RMSNorm over rows of 2560 ----------
__global__ __launch_bounds__(256)
void k_rmsnorm(const uint16_t* __restrict__ X, const float* __restrict__ g, uint16_t* __restrict__ Y)
{
  const int row = blockIdx.x;
  const int tid = threadIdx.x;
  const uint16_t* x = X + (size_t)row * 2560;
  float ss = 0.f;
  #pragma unroll
  for (int it = 0; it < 10; ++it) {
    const int i = tid + it * 256;
    const float v = bf2f(x[i]);
    ss += v * v;
  }
  #pragma unroll
  for (int off = 1; off < 64; off <<= 1) ss += __shfl_xor(ss, off, 64);
  __shared__ float sred[4];
  if ((tid & 63) == 0) sred[tid >> 6] = ss;
  __syncthreads();
  const float tot = sred[0] + sred[1] + sred[2] + sred[3];
  const float rs = rsqrtf(tot * (1.0f / 2560.0f) + 1e-6f);
  uint16_t* y = Y + (size_t)row * 2560;
  #pragma unroll
  for (int it = 0; it < 10; ++it) {
    const int i = tid + it * 256;
    y[i] = f2bf(bf2f(x[i]) * rs * g[i]);
  }
}

// ---------- launch ----------
extern "C" void kernel_launch(void* const* d_in, const int* in_sizes, int n_in,
                              void* d_out, int out_size, void* d_ws, size_t ws_size,
                              hipStream_t stream)
{
  const float*    x     = (const float*)d_in[0];
  // d_in[1] = attention_mask (pure causal -> analytic)
  const uint32_t* qw    = (const uint32_t*)d_in[2];  // harness promotes uint8 -> int32
  const uint32_t* kw    = (const uint32_t*)d_in[3];
  const uint32_t* vw    = (const uint32_t*)d_in[4];
  const uint32_t* ow    = (const uint32_t*)d_in[5];
  const float*    qs    = (const float*)d_in[6];
  const float*    ks    = (const float*)d_in[7];
  const float*    vs    = (const float*)d_in[8];
  const float*    os    = (const float*)d_in[9];
  const float*    gnorm = (const float*)d_in[10];

  char* ws = (char*)d_ws;
  uint16_t* xb   = (uint16_t*)(ws + 0);         // 4096x2560 bf16 (x; reused as attn-out)
  uint16_t* wqkv = (uint16_t*)(ws + 20971520);  // 3840x2560 bf16
  uint16_t* owb  = (uint16_t*)(ws + 40632320);  // 2560x2560 bf16
  float*    cosT = (float*)   (ws + 53739520);  // 2048x64 f32
  float*    sinT = (float*)   (ws + 54263808);  // 2048x64 f32
  uint16_t* Qb   = (uint16_t*)(ws + 54788096);  // 4096x2560 bf16 (reused as normed)
  uint16_t* Kb   = (uint16_t*)(ws + 75759616);  // 4096x640 bf16
  uint16_t* Vt   = (uint16_t*)(ws + 81002496);  // 10x128x2048 bf16

  k_f32_to_bf16<<<10240, 256, 0, stream>>>(x, xb, 2621440);
  k_unpack<<<6400, 256, 0, stream>>>(qw, wqkv, 1638400, 640);
  k_unpack<<<1600, 256, 0, stream>>>(kw, wqkv + (size_t)2560 * 2560, 409600, 640);
  k_unpack<<<1600, 256, 0, stream>>>(vw, wqkv + (size_t)3200 * 2560, 409600, 640);
  k_unpack<<<6400, 256, 0, stream>>>(ow, owb, 1638400, 640);
  k_rope_table<<<512, 256, 0, stream>>>(cosT, sinT);

  k_gemm<0><<<dim3(30, 32), 256, 0, stream>>>(xb, wqkv, Qb, Kb, Vt, nullptr,
                                              qs, ks, vs, 4096, 3840, 2560);
  k_rope<<<20480, 256, 0, stream>>>(Qb, cosT, sinT, 20, 5242880);
  k_rope<<<5120, 256, 0, stream>>>(Kb, cosT, sinT, 5, 1310720);

  k_attn<<<dim3(64, 10), 256, 0, stream>>>(Qb, Kb, Vt, xb);

  k_rmsnorm<<<4096, 256, 0, stream>>>(xb, gnorm, Qb);

  k_gemm<1><<<dim3(20, 32), 256, 0, stream>>>(Qb, owb, nullptr, nullptr, nullptr,
                                              (float*)d_out, os, nullptr, nullptr,
                                              4096, 2560, 2560);
}